// Round 1
// 544.795 us; speedup vs baseline: 1.3299x; 1.3299x over previous
//
#include <hip/hip_runtime.h>
#include <hip/hip_fp16.h>

// Problem constants
#define NCLS 512
#define COUT 256
#define BB 4
#define TT 16
#define HH 64
#define WW 64

static constexpr size_t TABLE_ELEMS = 27ull * NCLS * COUT;   // half elements
static constexpr size_t TABLE_BYTES = TABLE_ELEMS * sizeof(__half);

// ---------------------------------------------------------------------------
// Kernel 1: repack weight (C=256, N=512, 27) fp32 -> table[27][512][256p] half
// with PERMUTED channel order: table col p holds original channel
//   c(p) = (p&7)*32 + (p>>3)
// so a lane's dwordx4 (8 consecutive table cols 8l..8l+7) holds original
// channels {l, 32+l, 64+l, ...} -> conflict-free LDS transpose in kernel 2.
// Thread = p (writes coalesced); reads are per-thread 108 B runs (L1-cached).
// ---------------------------------------------------------------------------
__global__ __launch_bounds__(256) void repack_kernel(const float* __restrict__ w,
                                                     __half* __restrict__ tbl) {
    int n = blockIdx.x;                      // 0..511
    int p = threadIdx.x;                     // table column 0..255
    int c = ((p & 7) << 5) + (p >> 3);       // original channel
    const float* src = w + ((size_t)c * NCLS + n) * 27;
    float v[27];
#pragma unroll
    for (int k = 0; k < 27; ++k) v[k] = src[k];
#pragma unroll
    for (int k = 0; k < 27; ++k)
        tbl[((size_t)k * NCLS + n) * COUT + p] = __float2half(v[k]);
}

// ---------------------------------------------------------------------------
// Kernel 2: main gather-accumulate.
// Block = one (b,t,h): 4096 blocks x 256 threads, XCD-swizzled (8 x 512).
// Half-wave pairing: lanes 0-31 serve w position A, lanes 32-63 serve A+1.
// Lane reads 16 B (8 permuted channels) per tap -> one 2x512B coalesced
// dwordx4 per wave per tap. Per pair: stage 9 LDS index offsets into regs,
// issue 9 independent loads, then accumulate (deep MLP, ~9 KB in flight).
// ---------------------------------------------------------------------------
__global__ __launch_bounds__(256, 4) void conv_kernel(const int* __restrict__ idx,
                                                      const __half* __restrict__ tbl,
                                                      const float* __restrict__ bias,
                                                      float* __restrict__ out) {
    __shared__ int soff[3 * 3 * 66];      // per-tap-row byte offsets (n << 9)
    __shared__ float tile[16 * 256];      // [w16][c] staging, 16 KB

    // XCD swizzle: consecutive original bids (h-adjacent, sharing 2/3 of
    // gather rows) land on the same XCD's L2. 4096 = 8 * 512 exactly.
    int bid = ((blockIdx.x & 7) << 9) | (blockIdx.x >> 3);
    int h = bid & 63;
    int t = (bid >> 6) & 15;
    int b = bid >> 10;
    int tid = threadIdx.x;

    // ---- stage clamped row byte-offsets for the (3 dt)x(3 dh)x(66 w) window
    for (int e = tid; e < 594; e += 256) {
        int tt = e / 198;
        int r  = e - tt * 198;
        int hh = r / 66;
        int ww = r - hh * 66;
        int ts = t + tt - 2; if (ts < 0) ts = 0;                 // edge pad (2,0)
        int hs = h + hh - 1; if (hs < 0) hs = 0; if (hs > 63) hs = 63;
        int ws = ww - 1;     if (ws < 0) ws = 0; if (ws > 63) ws = 63;
        int n = idx[(((b * TT + ts) * HH) + hs) * WW + ws];
        soff[e] = n << 9;                                        // n * 512 bytes
    }
    __syncthreads();

    int lane = tid & 63;
    int wave = tid >> 6;
    int half = lane >> 5;                 // which w of the pair
    int l5   = lane & 31;
    const char* tb = (const char*)tbl + l5 * 16;   // this lane's 16 B column slot

    for (int chunk = 0; chunk < 4; ++chunk) {
#pragma unroll
        for (int pr = 0; pr < 2; ++pr) {
            int w16 = (wave << 2) + (pr << 1) + half;   // 0..15, unique per lane-half
            int w   = (chunk << 4) + w16;               // this lane's output w
            __half2 a0 = __float2half2_rn(0.0f);
            __half2 a1 = a0, a2 = a0, a3 = a0;
#pragma unroll
            for (int g = 0; g < 3; ++g) {               // 3 groups of 9 taps
                int no[9];
#pragma unroll
                for (int i = 0; i < 9; ++i) {
                    int kt = g * 3 + i / 3;             // tap row (dt*3+dh)
                    int dw = i % 3;
                    no[i] = soff[kt * 66 + w + dw];
                }
                uint4 ld[9];
#pragma unroll
                for (int i = 0; i < 9; ++i) {
                    int k = g * 9 + i;                  // tap 0..26
                    ld[i] = *reinterpret_cast<const uint4*>(tb + (no[i] + k * 262144));
                }
#pragma unroll
                for (int i = 0; i < 9; ++i) {
                    union { uint4 u; __half2 h2[4]; } v; v.u = ld[i];
                    a0 = __hadd2(a0, v.h2[0]);
                    a1 = __hadd2(a1, v.h2[1]);
                    a2 = __hadd2(a2, v.h2[2]);
                    a3 = __hadd2(a3, v.h2[3]);
                }
            }
            // half index i within the uint4 is original channel 32*i + l5:
            // scalar stores at stride 32 dwords -> banks == l5, conflict-free.
            float2 f0 = __half22float2(a0);
            float2 f1 = __half22float2(a1);
            float2 f2 = __half22float2(a2);
            float2 f3 = __half22float2(a3);
            float* tw = &tile[w16 * 256 + l5];
            tw[0]   = f0.x; tw[32]  = f0.y;
            tw[64]  = f1.x; tw[96]  = f1.y;
            tw[128] = f2.x; tw[160] = f2.y;
            tw[192] = f3.x; tw[224] = f3.y;
        }
        __syncthreads();

        // ---- store phase: thread = channel; 16 contiguous w per channel
        {
            int c = tid;
            float bv = bias[c];
            float* obase = out + ((((size_t)b * COUT + c) * TT + t) * HH + h) * WW
                               + (chunk << 4);
#pragma unroll
            for (int q = 0; q < 4; ++q) {
                float4 v;
                v.x = tile[(q * 4 + 0) * 256 + c] + bv;
                v.y = tile[(q * 4 + 1) * 256 + c] + bv;
                v.z = tile[(q * 4 + 2) * 256 + c] + bv;
                v.w = tile[(q * 4 + 3) * 256 + c] + bv;
                *reinterpret_cast<float4*>(obase + q * 4) = v;
            }
        }
        __syncthreads();
    }
}

// ---------------------------------------------------------------------------
// Fallback (only if workspace is too small for the half table): direct fp32
// gather from the original layout. Slow but correct.
// ---------------------------------------------------------------------------
__global__ __launch_bounds__(256) void conv_direct(const int* __restrict__ idx,
                                                   const float* __restrict__ wgt,
                                                   const float* __restrict__ bias,
                                                   float* __restrict__ out) {
    int bid = blockIdx.x;                 // b*65536 + t*4096 + h*64 + w
    int w = bid & 63;
    int h = (bid >> 6) & 63;
    int t = (bid >> 12) & 15;
    int b = bid >> 16;
    int c = threadIdx.x;
    float acc = bias[c];
#pragma unroll
    for (int dt = 0; dt < 3; ++dt)
#pragma unroll
        for (int dh = 0; dh < 3; ++dh)
#pragma unroll
            for (int dw = 0; dw < 3; ++dw) {
                int ts = t + dt - 2; if (ts < 0) ts = 0;
                int hs = h + dh - 1; if (hs < 0) hs = 0; if (hs > 63) hs = 63;
                int ws = w + dw - 1; if (ws < 0) ws = 0; if (ws > 63) ws = 63;
                int n = idx[(((b * TT + ts) * HH) + hs) * WW + ws];
                acc += wgt[((size_t)(c * NCLS + n)) * 27 + (dt * 9 + dh * 3 + dw)];
            }
    out[((((size_t)b * COUT + c) * TT + t) * HH + h) * WW + w] = acc;
}

extern "C" void kernel_launch(void* const* d_in, const int* in_sizes, int n_in,
                              void* d_out, int out_size, void* d_ws, size_t ws_size,
                              hipStream_t stream) {
    const int*   indices = (const int*)d_in[0];
    const float* weight  = (const float*)d_in[1];
    const float* bias    = (const float*)d_in[2];
    float*       out     = (float*)d_out;

    if (ws_size >= TABLE_BYTES) {
        __half* tbl = (__half*)d_ws;
        repack_kernel<<<NCLS, 256, 0, stream>>>(weight, tbl);
        conv_kernel<<<BB * TT * HH, 256, 0, stream>>>(indices, tbl, bias, out);
    } else {
        conv_direct<<<BB * TT * HH * WW, 256, 0, stream>>>(indices, weight, bias, out);
    }
}